// Round 1
// baseline (525.562 us; speedup 1.0000x reference)
//
#include <hip/hip_runtime.h>
#include <math.h>

#define T_LEN 4096
#define C_LEN 256
#define B_LEN 16

// ---------------------------------------------------------------------------
// Compile-time Gaussian kernel bank (matches numpy: exp(-0.5*(j/s)^2), trunc
// at r=int(4*s), normalized by sum+1e-12). Values become instruction literals.
// ---------------------------------------------------------------------------
constexpr double cexp(double x) {
    double y = x * (1.0 / 1024.0);
    double t = 1.0, term = 1.0;
    for (int i = 1; i <= 12; ++i) { term *= y / i; t += term; }
    for (int i = 0; i < 10; ++i) t = t * t;   // ^1024
    return t;
}

constexpr int RAD[5] = {10, 16, 24, 36, 56};

struct Bank { float g[5][57]; };

constexpr Bank make_bank() {
    Bank b{};
    const double sig[5] = {2.5, 4.0, 6.0, 9.0, 14.0};
    for (int k = 0; k < 5; ++k) {
        double w[57] = {};
        for (int j = 0; j <= RAD[k]; ++j)
            w[j] = cexp(-0.5 * (double)(j * j) / (sig[k] * sig[k]));
        double s = w[0];
        for (int j = 1; j <= RAD[k]; ++j) s += 2.0 * w[j];
        s += 1e-12;
        for (int j = 0; j <= RAD[k]; ++j) b.g[k][j] = (float)(w[j] / s);
    }
    return b;
}

constexpr Bank BANK = make_bank();

// ---------------------------------------------------------------------------
// Exact-ish GELU: 0.5*x*(1+erf(x/sqrt(2))), erf via A&S 7.1.26 (|err|<=1.5e-7)
// ---------------------------------------------------------------------------
__device__ __forceinline__ float gelu_erf(float v) {
    const float p  = 0.3275911f;
    const float a1 = 0.254829592f, a2 = -0.284496736f, a3 = 1.421413741f;
    const float a4 = -1.453152027f, a5 = 1.061405429f;
    float u  = v * 0.70710678118654752f;
    float au = fabsf(u);
    float t  = __builtin_amdgcn_rcpf(fmaf(p, au, 1.0f));
    float P  = t * fmaf(t, fmaf(t, fmaf(t, fmaf(t, a5, a4), a3), a2), a1);
    float E  = __expf(-u * u);
    float er = fmaf(-P, E, 1.0f);          // erf(|u|)
    er = copysignf(er, u);
    return 0.5f * v * (1.0f + er);
}

__device__ __forceinline__ float ldz(const float* __restrict__ xb, int tt) {
    if (tt < 0 || tt >= T_LEN) return 0.0f;
    return xb[tt * C_LEN];
}

// ---------------------------------------------------------------------------
// Per-thread worker: one channel c, 4 consecutive t starting at t0.
// CHECKED=true handles series edges (zero-pad conv, reflect-pad pooling).
// ---------------------------------------------------------------------------
template <bool CHECKED>
__device__ __forceinline__ void work(const float* __restrict__ x,
                                     const float* __restrict__ b2,
                                     float* __restrict__ out,
                                     const float (*__restrict__ wle)[8],
                                     const float* __restrict__ w2e,
                                     int b, int t0, int c) {
    const float* xb = x + (size_t)b * T_LEN * C_LEN + c;  // index by t*C_LEN

    // ---- pooling window values: x[t0-7 .. t0+11] (reflect at edges) ----
    float v[19];
#pragma unroll
    for (int i = 0; i < 19; ++i) {
        int tt = t0 - 7 + i;
        if (CHECKED) {
            tt = (tt < 0) ? -tt : tt;
            tt = (tt >= T_LEN) ? (2 * T_LEN - 2 - tt) : tt;
        }
        v[i] = xb[tt * C_LEN];
    }

    float mean[4], var[4], xc[4];
    {
        float s = 0.f, q = 0.f;
#pragma unroll
        for (int i = 0; i < 16; ++i) { s += v[i]; q = fmaf(v[i], v[i], q); }
#pragma unroll
        for (int m = 0; m < 4; ++m) {
            if (m > 0) {
                float nw = v[15 + m], od = v[m - 1];
                s = s + nw - od;
                q = fmaf(nw, nw, fmaf(od, -od, q));
            }
            mean[m] = s * 0.0625f;
            float m2 = q * 0.0625f;
            float vv = fmaf(-mean[m], mean[m], m2);
            var[m] = vv > 0.f ? vv : 0.f;
            xc[m]  = v[7 + m];   // x[t0+m] (always in range -> reflect is identity)
        }
    }

    // ---- 5 Gaussian convs, symmetric-pair register sliding windows ----
    float acc[5][4];
#pragma unroll
    for (int k = 0; k < 5; ++k)
#pragma unroll
        for (int m = 0; m < 4; ++m) acc[k][m] = BANK.g[k][0] * xc[m];

    float F[4], Bw[4];
    if (CHECKED) {
        F[1] = ldz(xb, t0 + 1); F[2] = ldz(xb, t0 + 2);
        F[3] = ldz(xb, t0 + 3); F[0] = ldz(xb, t0 + 4);
        Bw[3] = ldz(xb, t0 - 1); Bw[0] = ldz(xb, t0);
        Bw[1] = ldz(xb, t0 + 1); Bw[2] = ldz(xb, t0 + 2);
    } else {
        F[1] = v[8]; F[2] = v[9]; F[3] = v[10]; F[0] = v[11];
        Bw[3] = v[6]; Bw[0] = v[7]; Bw[1] = v[8]; Bw[2] = v[9];
    }

#pragma unroll
    for (int j = 1; j <= 56; ++j) {
        float sm[4];
#pragma unroll
        for (int m = 0; m < 4; ++m)
            sm[m] = F[(j + m) & 3] + Bw[(m - j) & 3];
#pragma unroll
        for (int k = 0; k < 5; ++k) {
            if (j <= RAD[k]) {
#pragma unroll
                for (int m = 0; m < 4; ++m)
                    acc[k][m] = fmaf(BANK.g[k][j], sm[m], acc[k][m]);
            }
        }
        if (j < 56) {
            if (CHECKED) {
                F[j & 3]        = ldz(xb, t0 + j + 4);
                Bw[(3 - j) & 3] = ldz(xb, t0 - j - 1);
            } else {
                F[j & 3]        = (j <= 7) ? v[j + 11] : xb[(t0 + j + 4) * C_LEN];
                Bw[(3 - j) & 3] = (j <= 6) ? v[6 - j]  : xb[(t0 - j - 1) * C_LEN];
            }
        }
    }

    // ---- conditioner MLP: 3 -> 32 (exact GELU) -> 5 logits ----
    float lg[5][4];
#pragma unroll
    for (int k = 0; k < 5; ++k) {
        float bk = b2[k];
#pragma unroll
        for (int m = 0; m < 4; ++m) lg[k][m] = bk;
    }

#pragma unroll 2
    for (int i = 0; i < 32; ++i) {
        float4 wa = *(const float4*)&wle[i][0];  // w1_0, w1_1, w1_2, b1
        float4 wb = *(const float4*)&wle[i][4];  // w2_0..w2_3
        float w24 = w2e[i];                      // w2_4
#pragma unroll
        for (int m = 0; m < 4; ++m) {
            float pre = fmaf(wa.x, mean[m], fmaf(wa.y, var[m], fmaf(wa.z, xc[m], wa.w)));
            float h = gelu_erf(pre);
            lg[0][m] = fmaf(h, wb.x, lg[0][m]);
            lg[1][m] = fmaf(h, wb.y, lg[1][m]);
            lg[2][m] = fmaf(h, wb.z, lg[2][m]);
            lg[3][m] = fmaf(h, wb.w, lg[3][m]);
            lg[4][m] = fmaf(h, w24,  lg[4][m]);
        }
    }

    // ---- softmax over K=5 + mixture, store ----
#pragma unroll
    for (int m = 0; m < 4; ++m) {
        float l0 = lg[0][m], l1 = lg[1][m], l2 = lg[2][m], l3 = lg[3][m], l4 = lg[4][m];
        float mx = fmaxf(fmaxf(fmaxf(l0, l1), fmaxf(l2, l3)), l4);
        float e0 = __expf(l0 - mx), e1 = __expf(l1 - mx), e2 = __expf(l2 - mx);
        float e3 = __expf(l3 - mx), e4 = __expf(l4 - mx);
        float den = ((e0 + e1) + (e2 + e3)) + e4;
        float num = e0 * acc[0][m];
        num = fmaf(e1, acc[1][m], num);
        num = fmaf(e2, acc[2][m], num);
        num = fmaf(e3, acc[3][m], num);
        num = fmaf(e4, acc[4][m], num);
        out[((size_t)b * T_LEN + t0 + m) * C_LEN + c] = num * __builtin_amdgcn_rcpf(den);
    }
}

// ---------------------------------------------------------------------------
// Kernels: interior (no range checks) + boundary (28 edge chunks per b)
// ---------------------------------------------------------------------------
#define STAGE_WEIGHTS()                                                        \
    __shared__ __align__(16) float wle[32][8];                                 \
    __shared__ float w2e[32];                                                  \
    {                                                                          \
        int tid = threadIdx.x;                                                 \
        if (tid < 32) {                                                        \
            wle[tid][0] = W1[tid];                                             \
            wle[tid][1] = W1[32 + tid];                                        \
            wle[tid][2] = W1[64 + tid];                                        \
            wle[tid][3] = b1[tid];                                             \
            wle[tid][4] = W2[tid * 5 + 0];                                     \
            wle[tid][5] = W2[tid * 5 + 1];                                     \
            wle[tid][6] = W2[tid * 5 + 2];                                     \
            wle[tid][7] = W2[tid * 5 + 3];                                     \
            w2e[tid]    = W2[tid * 5 + 4];                                     \
        }                                                                      \
        __syncthreads();                                                       \
    }

__global__ __launch_bounds__(256) void agt_interior(
    const float* __restrict__ x, const float* __restrict__ W1,
    const float* __restrict__ b1, const float* __restrict__ W2,
    const float* __restrict__ b2, float* __restrict__ out) {
    STAGE_WEIGHTS();
    // 996 interior chunks per b: chunk 14..1009  (t0 in [56, 4036])
    int b     = blockIdx.x / 996;
    int chunk = 14 + (blockIdx.x - b * 996);
    int t0    = chunk * 4;
    work<false>(x, b2, out, wle, w2e, b, t0, threadIdx.x);
}

__global__ __launch_bounds__(256) void agt_boundary(
    const float* __restrict__ x, const float* __restrict__ W1,
    const float* __restrict__ b1, const float* __restrict__ W2,
    const float* __restrict__ b2, float* __restrict__ out) {
    STAGE_WEIGHTS();
    // 28 boundary chunks per b: 0..13 and 1010..1023
    int b    = blockIdx.x / 28;
    int cidx = blockIdx.x - b * 28;
    int chunk = (cidx < 14) ? cidx : (996 + cidx);
    int t0    = chunk * 4;
    work<true>(x, b2, out, wle, w2e, b, t0, threadIdx.x);
}

extern "C" void kernel_launch(void* const* d_in, const int* in_sizes, int n_in,
                              void* d_out, int out_size, void* d_ws, size_t ws_size,
                              hipStream_t stream) {
    const float* x  = (const float*)d_in[0];
    const float* W1 = (const float*)d_in[1];
    const float* b1 = (const float*)d_in[2];
    const float* W2 = (const float*)d_in[3];
    const float* b2 = (const float*)d_in[4];
    float* out = (float*)d_out;

    (void)in_sizes; (void)n_in; (void)d_ws; (void)ws_size; (void)out_size;

    dim3 blk(256);
    agt_interior<<<dim3(B_LEN * 996), blk, 0, stream>>>(x, W1, b1, W2, b2, out);
    agt_boundary<<<dim3(B_LEN * 28),  blk, 0, stream>>>(x, W1, b1, W2, b2, out);
}

// Round 2
// 427.367 us; speedup vs baseline: 1.2298x; 1.2298x over previous
//
#include <hip/hip_runtime.h>
#include <math.h>

#define T_LEN 4096
#define C_LEN 256
#define B_LEN 16

// ---------------------------------------------------------------------------
// Compile-time Gaussian kernel bank (matches numpy: exp(-0.5*(j/s)^2), trunc
// at r=int(4*s), normalized by sum+1e-12). Values become instruction literals.
// ---------------------------------------------------------------------------
constexpr double cexp(double x) {
    double y = x * (1.0 / 1024.0);
    double t = 1.0, term = 1.0;
    for (int i = 1; i <= 12; ++i) { term *= y / i; t += term; }
    for (int i = 0; i < 10; ++i) t = t * t;   // ^1024
    return t;
}

constexpr int RAD[5] = {10, 16, 24, 36, 56};

struct Bank { float g[5][57]; };

constexpr Bank make_bank() {
    Bank b{};
    const double sig[5] = {2.5, 4.0, 6.0, 9.0, 14.0};
    for (int k = 0; k < 5; ++k) {
        double w[57] = {};
        for (int j = 0; j <= RAD[k]; ++j)
            w[j] = cexp(-0.5 * (double)(j * j) / (sig[k] * sig[k]));
        double s = w[0];
        for (int j = 1; j <= RAD[k]; ++j) s += 2.0 * w[j];
        s += 1e-12;
        for (int j = 0; j <= RAD[k]; ++j) b.g[k][j] = (float)(w[j] / s);
    }
    return b;
}

constexpr Bank BANK = make_bank();

#define LOG2E 1.4426950408889634f

__device__ __forceinline__ float fast_exp2(float x) {
#if __has_builtin(__builtin_amdgcn_exp2f)
    return __builtin_amdgcn_exp2f(x);
#else
    return __expf(x * 0.6931471805599453f);
#endif
}

// ---------------------------------------------------------------------------
// Fast GELU (tanh form): x * sigmoid(1.5957691216*(x + 0.044715 x^3)).
// Max |err| vs exact-erf GELU ~4e-4/unit -> ~2e-3 on final output (budget
// 2.4e-2, measured baseline absmax 3.9e-3). exp2 with log2e pre-folded:
// ~13 issue-slots vs ~22 for the erf version (2 quarter-rate transcendentals).
// Saturation: v->-inf => z->+inf => exp2=inf => rcp=0 => h=0 (correct).
// ---------------------------------------------------------------------------
__device__ __forceinline__ float gelu_fast(float v) {
    const float c1 = (float)(-2.0 * 0.7978845608028654 * 1.4426950408889634);
    const float c2 = c1 * 0.044715f;
    float v2 = v * v;
    float t  = fmaf(c2, v2, c1);
    float z  = v * t;                         // -log2e * 2*0.79788*(v+0.044715 v^3)
    float e  = fast_exp2(z);
    float r  = __builtin_amdgcn_rcpf(1.0f + e);
    return v * r;
}

__device__ __forceinline__ float ldz(const float* __restrict__ xb, int tt) {
    if (tt < 0 || tt >= T_LEN) return 0.0f;
    return xb[tt * C_LEN];
}

// ---------------------------------------------------------------------------
// Per-thread worker: one channel c, 4 consecutive t starting at t0.
// CHECKED=true handles series edges (zero-pad conv, reflect-pad pooling).
// ---------------------------------------------------------------------------
template <bool CHECKED>
__device__ __forceinline__ void work(const float* __restrict__ x,
                                     float* __restrict__ out,
                                     const float (*__restrict__ wle)[8],
                                     const float* __restrict__ w2e,
                                     const float* __restrict__ b2l,
                                     int b, int t0, int c) {
    const float* xb = x + (size_t)b * T_LEN * C_LEN + c;  // index by t*C_LEN

    // ---- pooling window values: x[t0-7 .. t0+11] (reflect at edges) ----
    float v[19];
#pragma unroll
    for (int i = 0; i < 19; ++i) {
        int tt = t0 - 7 + i;
        if (CHECKED) {
            tt = (tt < 0) ? -tt : tt;
            tt = (tt >= T_LEN) ? (2 * T_LEN - 2 - tt) : tt;
        }
        v[i] = xb[tt * C_LEN];
    }

    float mean[4], var[4], xc[4];
    {
        float s = 0.f, q = 0.f;
#pragma unroll
        for (int i = 0; i < 16; ++i) { s += v[i]; q = fmaf(v[i], v[i], q); }
#pragma unroll
        for (int m = 0; m < 4; ++m) {
            if (m > 0) {
                float nw = v[15 + m], od = v[m - 1];
                s = s + nw - od;
                q = fmaf(nw, nw, fmaf(od, -od, q));
            }
            mean[m] = s * 0.0625f;
            float m2 = q * 0.0625f;
            float vv = fmaf(-mean[m], mean[m], m2);
            var[m] = vv > 0.f ? vv : 0.f;
            xc[m]  = v[7 + m];   // x[t0+m] (always in range -> reflect is identity)
        }
    }

    // ---- 5 Gaussian convs, symmetric-pair register sliding windows ----
    float acc[5][4];
#pragma unroll
    for (int k = 0; k < 5; ++k)
#pragma unroll
        for (int m = 0; m < 4; ++m) acc[k][m] = BANK.g[k][0] * xc[m];

    float F[4], Bw[4];
    if (CHECKED) {
        F[1] = ldz(xb, t0 + 1); F[2] = ldz(xb, t0 + 2);
        F[3] = ldz(xb, t0 + 3); F[0] = ldz(xb, t0 + 4);
        Bw[3] = ldz(xb, t0 - 1); Bw[0] = ldz(xb, t0);
        Bw[1] = ldz(xb, t0 + 1); Bw[2] = ldz(xb, t0 + 2);
    } else {
        F[1] = v[8]; F[2] = v[9]; F[3] = v[10]; F[0] = v[11];
        Bw[3] = v[6]; Bw[0] = v[7]; Bw[1] = v[8]; Bw[2] = v[9];
    }

#pragma unroll
    for (int j = 1; j <= 56; ++j) {
        float sm[4];
#pragma unroll
        for (int m = 0; m < 4; ++m)
            sm[m] = F[(j + m) & 3] + Bw[(m - j) & 3];
#pragma unroll
        for (int k = 0; k < 5; ++k) {
            if (j <= RAD[k]) {
#pragma unroll
                for (int m = 0; m < 4; ++m)
                    acc[k][m] = fmaf(BANK.g[k][j], sm[m], acc[k][m]);
            }
        }
        if (j < 56) {
            if (CHECKED) {
                F[j & 3]        = ldz(xb, t0 + j + 4);
                Bw[(3 - j) & 3] = ldz(xb, t0 - j - 1);
            } else {
                F[j & 3]        = (j <= 7) ? v[j + 11] : xb[(t0 + j + 4) * C_LEN];
                Bw[(3 - j) & 3] = (j <= 6) ? v[6 - j]  : xb[(t0 - j - 1) * C_LEN];
            }
        }
    }

    // ---- conditioner MLP: 3 -> 32 (fast GELU) -> 5 logits (pre-scaled by
    // log2e at weight-staging time so softmax uses raw v_exp_f32) ----
    float lg[5][4];
#pragma unroll
    for (int k = 0; k < 5; ++k) {
        float bk = b2l[k];
#pragma unroll
        for (int m = 0; m < 4; ++m) lg[k][m] = bk;
    }

#pragma unroll 2
    for (int i = 0; i < 32; ++i) {
        float4 wa = *(const float4*)&wle[i][0];  // w1_0, w1_1, w1_2, b1
        float4 wb = *(const float4*)&wle[i][4];  // w2_0..w2_3  (x log2e)
        float w24 = w2e[i];                      // w2_4        (x log2e)
#pragma unroll
        for (int m = 0; m < 4; ++m) {
            float pre = fmaf(wa.x, mean[m], fmaf(wa.y, var[m], fmaf(wa.z, xc[m], wa.w)));
            float h = gelu_fast(pre);
            lg[0][m] = fmaf(h, wb.x, lg[0][m]);
            lg[1][m] = fmaf(h, wb.y, lg[1][m]);
            lg[2][m] = fmaf(h, wb.z, lg[2][m]);
            lg[3][m] = fmaf(h, wb.w, lg[3][m]);
            lg[4][m] = fmaf(h, w24 , lg[4][m]);
        }
    }

    // ---- softmax over K=5 (logits already x log2e) + mixture, store ----
#pragma unroll
    for (int m = 0; m < 4; ++m) {
        float l0 = lg[0][m], l1 = lg[1][m], l2 = lg[2][m], l3 = lg[3][m], l4 = lg[4][m];
        float mx = fmaxf(fmaxf(fmaxf(l0, l1), fmaxf(l2, l3)), l4);
        float e0 = fast_exp2(l0 - mx), e1 = fast_exp2(l1 - mx), e2 = fast_exp2(l2 - mx);
        float e3 = fast_exp2(l3 - mx), e4 = fast_exp2(l4 - mx);
        float den = ((e0 + e1) + (e2 + e3)) + e4;
        float num = e0 * acc[0][m];
        num = fmaf(e1, acc[1][m], num);
        num = fmaf(e2, acc[2][m], num);
        num = fmaf(e3, acc[3][m], num);
        num = fmaf(e4, acc[4][m], num);
        out[((size_t)b * T_LEN + t0 + m) * C_LEN + c] = num * __builtin_amdgcn_rcpf(den);
    }
}

// ---------------------------------------------------------------------------
// Single fused kernel: boundary chunks (28/1024 per b) take the CHECKED path,
// block-uniform branch; boundary work overlaps interior (was a serialized
// second kernel costing ~60 us).
// ---------------------------------------------------------------------------
__global__ __launch_bounds__(256) void agt_fused(
    const float* __restrict__ x, const float* __restrict__ W1,
    const float* __restrict__ b1, const float* __restrict__ W2,
    const float* __restrict__ b2, float* __restrict__ out) {
    __shared__ __align__(16) float wle[32][8];
    __shared__ float w2e[32];
    __shared__ float b2l[5];
    {
        int tid = threadIdx.x;
        if (tid < 32) {
            wle[tid][0] = W1[tid];
            wle[tid][1] = W1[32 + tid];
            wle[tid][2] = W1[64 + tid];
            wle[tid][3] = b1[tid];
            wle[tid][4] = W2[tid * 5 + 0] * LOG2E;
            wle[tid][5] = W2[tid * 5 + 1] * LOG2E;
            wle[tid][6] = W2[tid * 5 + 2] * LOG2E;
            wle[tid][7] = W2[tid * 5 + 3] * LOG2E;
            w2e[tid]    = W2[tid * 5 + 4] * LOG2E;
            if (tid < 5) b2l[tid] = b2[tid] * LOG2E;
        }
        __syncthreads();
    }
    int b     = blockIdx.x >> 10;        // 1024 chunks per batch
    int chunk = blockIdx.x & 1023;
    int t0    = chunk * 4;
    if (chunk >= 14 && chunk < 1010)
        work<false>(x, out, wle, w2e, b2l, b, t0, threadIdx.x);
    else
        work<true>(x, out, wle, w2e, b2l, b, t0, threadIdx.x);
}

extern "C" void kernel_launch(void* const* d_in, const int* in_sizes, int n_in,
                              void* d_out, int out_size, void* d_ws, size_t ws_size,
                              hipStream_t stream) {
    const float* x  = (const float*)d_in[0];
    const float* W1 = (const float*)d_in[1];
    const float* b1 = (const float*)d_in[2];
    const float* W2 = (const float*)d_in[3];
    const float* b2 = (const float*)d_in[4];
    float* out = (float*)d_out;

    (void)in_sizes; (void)n_in; (void)d_ws; (void)ws_size; (void)out_size;

    agt_fused<<<dim3(B_LEN * 1024), dim3(256), 0, stream>>>(x, W1, b1, W2, b2, out);
}